// Round 2
// baseline (488.217 us; speedup 1.0000x reference)
//
#include <hip/hip_runtime.h>
#include <cstdint>
#include <cstddef>

constexpr int V   = 128001;
constexpr int D   = 128;
constexpr int S   = 200;
constexpr int E   = 409600;
constexpr int G4  = 512;
constexpr int CAP = 8192;

__device__ __forceinline__ float rcp_fast(float x) {
    float r;
    asm volatile("v_rcp_f32 %0, %1" : "=v"(r) : "v"(x));
    return r;
}
__device__ __forceinline__ float sigmoid_fast(float x) {
    x = fminf(fmaxf(x, -15.f), 15.f);
    return rcp_fast(1.f + __expf(-x));
}
__device__ __forceinline__ float tanh_fast(float x) {
    x = fminf(fmaxf(x, -7.5f), 7.5f);
    float e = __expf(2.f * x);
    return (e - 1.f) * rcp_fast(e + 1.f);
}

// ---------------- degree pass + edge filter (dst % 200 == 199) ----------------
__global__ void k_deg_filter(const int* __restrict__ src, const int* __restrict__ dst,
                             int* __restrict__ deg_out, int* __restrict__ degr,
                             int* __restrict__ ecount, int2* __restrict__ elist)
{
    int e = blockIdx.x * blockDim.x + threadIdx.x;
    if (e >= E) return;
    int s = src[e], d = dst[e];
    atomicAdd(&deg_out[s], 1);
    if (d % S == S - 1) {
        int b = d / S;
        atomicAdd(&degr[b], 1);
        int p = atomicAdd(ecount, 1);
        if (p < CAP) elist[p] = make_int2(s, b);
    }
}

// ---------------- aggregate filtered edges ----------------
__global__ void k_agg(const int2* __restrict__ elist, const int* __restrict__ ecount,
                      const int* __restrict__ gnodes, const float* __restrict__ emb,
                      const int* __restrict__ deg_out, float* __restrict__ agg64)
{
    int cnt = *ecount; if (cnt > CAP) cnt = CAP;
    int idx = blockIdx.x * 2 + (threadIdx.x >> 7);
    int d   = threadIdx.x & 127;
    if (idx >= cnt) return;
    int2 eb = elist[idx];
    int s = eb.x, b = eb.y;
    int dg = deg_out[s];
    float ns = (dg > 0) ? rsqrtf((float)dg) : 0.f;
    float v = emb[(size_t)gnodes[s] * D + d] * ns;
    atomicAdd(&agg64[b * D + d], v);
}

// ---------------- h64 = relu((agg64 * n_dst) @ gW + gb), 64x128 ----------------
__global__ __launch_bounds__(512) void k_h64(const float* __restrict__ agg64,
                                             const int* __restrict__ degr,
                                             const float* __restrict__ gW,
                                             const float* __restrict__ gb,
                                             float* __restrict__ h64)
{
    __shared__ float a[64][128];
    for (int i = threadIdx.x; i < 64 * 128; i += blockDim.x) {
        int b = i >> 7;
        int dg = degr[b];
        float nd = (dg > 0) ? rsqrtf((float)dg) : 0.f;
        a[b][i & 127] = agg64[i] * nd;
    }
    __syncthreads();
    int j  = threadIdx.x & 127;
    int bg = threadIdx.x >> 7;
    float acc[16];
    float bias = gb[j];
#pragma unroll
    for (int ii = 0; ii < 16; ++ii) acc[ii] = bias;
    for (int k = 0; k < 128; ++k) {
        float w = gW[k * 128 + j];
#pragma unroll
        for (int ii = 0; ii < 16; ++ii) acc[ii] = fmaf(a[bg * 16 + ii][k], w, acc[ii]);
    }
#pragma unroll
    for (int ii = 0; ii < 16; ++ii)
        h64[(bg * 16 + ii) * 128 + j] = fmaxf(acc[ii], 0.f);
}

// ---------------- Gpre[t][u] = A[t] . Wih[u] + b1[u] + b2[u]  (64 x 512) ----------------
__global__ __launch_bounds__(256) void k_gemmG(const float* __restrict__ A,
                                               const float* __restrict__ Wih,
                                               const float* __restrict__ b1,
                                               const float* __restrict__ b2,
                                               float* __restrict__ Gpre)
{
    __shared__ float a[16][128];
    int tq = blockIdx.x >> 1;
    int ub = blockIdx.x & 1;
    for (int i = threadIdx.x; i < 16 * 128; i += 256)
        a[i >> 7][i & 127] = A[(tq * 16 + (i >> 7)) * 128 + (i & 127)];
    __syncthreads();
    int u = ub * 256 + threadIdx.x;
    float bias = b1[u] + b2[u];
    float acc[16];
#pragma unroll
    for (int t = 0; t < 16; ++t) acc[t] = bias;
    const float4* wr = reinterpret_cast<const float4*>(Wih + (size_t)u * 128);
    for (int k4 = 0; k4 < 32; ++k4) {
        float4 w4 = wr[k4];
#pragma unroll
        for (int t = 0; t < 16; ++t) {
            float4 av = *reinterpret_cast<const float4*>(&a[t][k4 * 4]);
            acc[t] += fmaf(w4.x, av.x, fmaf(w4.y, av.y, fmaf(w4.z, av.z, w4.w * av.w)));
        }
    }
#pragma unroll
    for (int t = 0; t < 16; ++t) Gpre[(tq * 16 + t) * G4 + u] = acc[t];
}

// ---------------- single-row LSTM recurrence, k-split by 2: 1024 threads ----------------
__global__ __launch_bounds__(1024, 4) void k_lstm(const float* __restrict__ Whh,   // 512 x 128
                                                  const float* __restrict__ Gpre,  // 64 x 512
                                                  const float* __restrict__ h0row, // 128
                                                  const float* __restrict__ c0row, // 128
                                                  float* __restrict__ hout)        // 64 x 128
{
    __shared__ float hbuf[2][128];
    __shared__ float part[2][512];
    const int tid = threadIdx.x;
    const int u = tid & 511;
    const int p = tid >> 9;               // k-half, uniform per wave
    float w[64];
    const float4* wr = reinterpret_cast<const float4*>(Whh + (size_t)u * 128 + (size_t)p * 64);
#pragma unroll
    for (int i = 0; i < 16; ++i) {
        float4 t4 = wr[i];
        w[4 * i + 0] = t4.x; w[4 * i + 1] = t4.y; w[4 * i + 2] = t4.z; w[4 * i + 3] = t4.w;
    }
    float c = 0.f;
    if (tid < 128) { hbuf[0][tid] = h0row[tid]; c = c0row[tid]; }
    __syncthreads();
    for (int t = 0; t < 64; ++t) {
        float gp = (p == 0) ? Gpre[t * G4 + u] : 0.f;
        const float* h = hbuf[t & 1] + p * 64;
        float a0 = 0.f, a1 = 0.f, a2 = 0.f, a3 = 0.f;
#pragma unroll
        for (int k = 0; k < 64; k += 4) {
            float4 hv = *reinterpret_cast<const float4*>(h + k);   // uniform broadcast
            a0 = fmaf(w[k + 0], hv.x, a0);
            a1 = fmaf(w[k + 1], hv.y, a1);
            a2 = fmaf(w[k + 2], hv.z, a2);
            a3 = fmaf(w[k + 3], hv.w, a3);
        }
        part[p][u] = gp + ((a0 + a1) + (a2 + a3));
        __syncthreads();
        if (tid < 128) {
            float gi = part[0][tid]       + part[1][tid];
            float gf = part[0][tid + 128] + part[1][tid + 128];
            float gg = part[0][tid + 256] + part[1][tid + 256];
            float go = part[0][tid + 384] + part[1][tid + 384];
            float si = sigmoid_fast(gi);
            float sf = sigmoid_fast(gf);
            float so = sigmoid_fast(go);
            c = sf * c + si * tanh_fast(gg);
            float hn = so * tanh_fast(c);
            hbuf[(t + 1) & 1][tid] = hn;
            hout[t * 128 + tid] = hn;
        }
        __syncthreads();
    }
}

// ---------------- logits: 64 x 128001, 4 v-rows x 16 b-cols per thread ----------------
__global__ __launch_bounds__(256) void k_fc(const float* __restrict__ out64,
                                            const float* __restrict__ fcW,
                                            const float* __restrict__ fcb,
                                            float* __restrict__ logits)
{
    __shared__ float ol[64][128];
    const int tid = threadIdx.x;
    const int bg  = blockIdx.y;            // 16-row b-group
    for (int i = tid; i < 64 * 128; i += 256) ol[i >> 7][i & 127] = out64[i];
    __syncthreads();
    const int vbase = blockIdx.x * 1024 + tid;
    int v[4];
    const float4* W[4];
    float acc[4][16];
#pragma unroll
    for (int i = 0; i < 4; ++i) {
        v[i] = vbase + i * 256;
        int vc = v[i] < V ? v[i] : V - 1;
        W[i] = reinterpret_cast<const float4*>(fcW + (size_t)vc * 128);
        float b = fcb[vc];
#pragma unroll
        for (int bb = 0; bb < 16; ++bb) acc[i][bb] = b;
    }
    for (int k4 = 0; k4 < 32; ++k4) {
        float4 w0 = W[0][k4], w1 = W[1][k4], w2 = W[2][k4], w3 = W[3][k4];
#pragma unroll
        for (int bb = 0; bb < 16; ++bb) {
            float4 a = *reinterpret_cast<const float4*>(&ol[bg * 16 + bb][k4 * 4]);  // broadcast
            acc[0][bb] += w0.x * a.x + w0.y * a.y + w0.z * a.z + w0.w * a.w;
            acc[1][bb] += w1.x * a.x + w1.y * a.y + w1.z * a.z + w1.w * a.w;
            acc[2][bb] += w2.x * a.x + w2.y * a.y + w2.z * a.z + w2.w * a.w;
            acc[3][bb] += w3.x * a.x + w3.y * a.y + w3.z * a.z + w3.w * a.w;
        }
    }
#pragma unroll
    for (int i = 0; i < 4; ++i) {
        if (v[i] < V) {
#pragma unroll
            for (int bb = 0; bb < 16; ++bb)
                logits[(size_t)(bg * 16 + bb) * V + v[i]] = acc[i][bb];
        }
    }
}

extern "C" void kernel_launch(void* const* d_in, const int* in_sizes, int n_in,
                              void* d_out, int out_size, void* d_ws, size_t ws_size,
                              hipStream_t stream)
{
    const int*   gnodes = (const int*)d_in[0];
    const int*   src    = (const int*)d_in[1];
    const int*   dst    = (const int*)d_in[2];
    const float* emb    = (const float*)d_in[3];
    const float* gW     = (const float*)d_in[4];
    const float* gb     = (const float*)d_in[5];
    const float* Wih0   = (const float*)d_in[6];
    const float* Whh0   = (const float*)d_in[7];
    const float* bih0   = (const float*)d_in[8];
    const float* bhh0   = (const float*)d_in[9];
    const float* Wih1   = (const float*)d_in[10];
    const float* Whh1   = (const float*)d_in[11];
    const float* bih1   = (const float*)d_in[12];
    const float* bhh1   = (const float*)d_in[13];
    const float* fcW    = (const float*)d_in[14];
    const float* fcb    = (const float*)d_in[15];
    const float* h0     = (const float*)d_in[16];  // (2, 200, 128)
    const float* c0     = (const float*)d_in[17];

    char* ws = (char*)d_ws;
    int*   deg_out = (int*)(ws + 0);          // 12800 ints
    int*   degr    = (int*)(ws + 51200);      // 64 ints
    int*   ecount  = (int*)(ws + 51456);      // 1 int (+pad)
    float* agg64   = (float*)(ws + 51712);    // 64*128  -> zero region ends at 84480
    int2*  elist   = (int2*)(ws + 84480);     // CAP entries (64 KB)
    float* h64     = (float*)(ws + 150016);   // 64*128
    float* Gpre    = (float*)(ws + 182784);   // 64*512
    float* h1out   = (float*)(ws + 313856);   // 64*128
    float* out64   = (float*)(ws + 346624);   // 64*128
    float* logits  = (float*)d_out;

    hipMemsetAsync(ws, 0, 84480, stream);     // deg_out, degr, ecount, agg64

    k_deg_filter<<<E / 256, 256, 0, stream>>>(src, dst, deg_out, degr, ecount, elist);
    k_agg<<<CAP / 2, 256, 0, stream>>>(elist, ecount, gnodes, emb, deg_out, agg64);
    k_h64<<<1, 512, 0, stream>>>(agg64, degr, gW, gb, h64);

    k_gemmG<<<8, 256, 0, stream>>>(h64, Wih0, bih0, bhh0, Gpre);
    k_lstm<<<1, 1024, 0, stream>>>(Whh0, Gpre, h0 + 199 * 128, c0 + 199 * 128, h1out);
    k_gemmG<<<8, 256, 0, stream>>>(h1out, Wih1, bih1, bhh1, Gpre);
    k_lstm<<<1, 1024, 0, stream>>>(Whh1, Gpre, h0 + (200 + 199) * 128, c0 + (200 + 199) * 128, out64);

    k_fc<<<dim3(126, 4), 256, 0, stream>>>(out64, fcW, fcb, logits);
}

// Round 3
// 258.644 us; speedup vs baseline: 1.8876x; 1.8876x over previous
//
#include <hip/hip_runtime.h>
#include <cstdint>
#include <cstddef>

constexpr int V   = 128001;
constexpr int D   = 128;
constexpr int S   = 200;
constexpr int E   = 409600;
constexpr int G4  = 512;
constexpr int CAP = 8192;

__device__ __forceinline__ float rcp_fast(float x) {
    float r;
    asm volatile("v_rcp_f32 %0, %1" : "=v"(r) : "v"(x));
    return r;
}
__device__ __forceinline__ float sigmoid_fast(float x) {
    x = fminf(fmaxf(x, -15.f), 15.f);
    return rcp_fast(1.f + __expf(-x));
}
__device__ __forceinline__ float tanh_fast(float x) {
    x = fminf(fmaxf(x, -7.5f), 7.5f);
    float e = __expf(2.f * x);
    return (e - 1.f) * rcp_fast(e + 1.f);
}

// ---------------- degree pass + edge filter (dst % 200 == 199) ----------------
__global__ void k_deg_filter(const int* __restrict__ src, const int* __restrict__ dst,
                             int* __restrict__ deg_out, int* __restrict__ degr,
                             int* __restrict__ ecount, int2* __restrict__ elist)
{
    int e = blockIdx.x * blockDim.x + threadIdx.x;
    if (e >= E) return;
    int s = src[e], d = dst[e];
    atomicAdd(&deg_out[s], 1);
    if (d % S == S - 1) {
        int b = d / S;
        atomicAdd(&degr[b], 1);
        int p = atomicAdd(ecount, 1);
        if (p < CAP) elist[p] = make_int2(s, b);
    }
}

// ---------------- aggregate filtered edges ----------------
__global__ void k_agg(const int2* __restrict__ elist, const int* __restrict__ ecount,
                      const int* __restrict__ gnodes, const float* __restrict__ emb,
                      const int* __restrict__ deg_out, float* __restrict__ agg64)
{
    int cnt = *ecount; if (cnt > CAP) cnt = CAP;
    int idx = blockIdx.x * 2 + (threadIdx.x >> 7);
    int d   = threadIdx.x & 127;
    if (idx >= cnt) return;
    int2 eb = elist[idx];
    int s = eb.x, b = eb.y;
    int dg = deg_out[s];
    float ns = (dg > 0) ? rsqrtf((float)dg) : 0.f;
    float v = emb[(size_t)gnodes[s] * D + d] * ns;
    atomicAdd(&agg64[b * D + d], v);
}

// ---------------- h64 = relu((agg64 * n_dst) @ gW + gb), 64x128 ----------------
__global__ __launch_bounds__(512) void k_h64(const float* __restrict__ agg64,
                                             const int* __restrict__ degr,
                                             const float* __restrict__ gW,
                                             const float* __restrict__ gb,
                                             float* __restrict__ h64)
{
    __shared__ float a[64][128];
    for (int i = threadIdx.x; i < 64 * 128; i += blockDim.x) {
        int b = i >> 7;
        int dg = degr[b];
        float nd = (dg > 0) ? rsqrtf((float)dg) : 0.f;
        a[b][i & 127] = agg64[i] * nd;
    }
    __syncthreads();
    int j  = threadIdx.x & 127;
    int bg = threadIdx.x >> 7;
    float acc[16];
    float bias = gb[j];
#pragma unroll
    for (int ii = 0; ii < 16; ++ii) acc[ii] = bias;
    for (int k = 0; k < 128; ++k) {
        float w = gW[k * 128 + j];
#pragma unroll
        for (int ii = 0; ii < 16; ++ii) acc[ii] = fmaf(a[bg * 16 + ii][k], w, acc[ii]);
    }
#pragma unroll
    for (int ii = 0; ii < 16; ++ii)
        h64[(bg * 16 + ii) * 128 + j] = fmaxf(acc[ii], 0.f);
}

// ---------------- Gpre[t][u] = A[t] . Wih[u] + b1[u] + b2[u]  (64 x 512) ----------------
__global__ __launch_bounds__(256) void k_gemmG(const float* __restrict__ A,
                                               const float* __restrict__ Wih,
                                               const float* __restrict__ b1,
                                               const float* __restrict__ b2,
                                               float* __restrict__ Gpre)
{
    __shared__ float a[16][128];
    int tq = blockIdx.x >> 1;
    int ub = blockIdx.x & 1;
    for (int i = threadIdx.x; i < 16 * 128; i += 256)
        a[i >> 7][i & 127] = A[(tq * 16 + (i >> 7)) * 128 + (i & 127)];
    __syncthreads();
    int u = ub * 256 + threadIdx.x;
    float bias = b1[u] + b2[u];
    float acc[16];
#pragma unroll
    for (int t = 0; t < 16; ++t) acc[t] = bias;
    const float4* wr = reinterpret_cast<const float4*>(Wih + (size_t)u * 128);
    for (int k4 = 0; k4 < 32; ++k4) {
        float4 w4 = wr[k4];
#pragma unroll
        for (int t = 0; t < 16; ++t) {
            float4 av = *reinterpret_cast<const float4*>(&a[t][k4 * 4]);
            acc[t] += fmaf(w4.x, av.x, fmaf(w4.y, av.y, fmaf(w4.z, av.z, w4.w * av.w)));
        }
    }
#pragma unroll
    for (int t = 0; t < 16; ++t) Gpre[(tq * 16 + t) * G4 + u] = acc[t];
}

// ---------------- single-row LSTM recurrence, k-split by 2: 1024 threads ----------------
__global__ __launch_bounds__(1024, 4) void k_lstm(const float* __restrict__ Whh,   // 512 x 128
                                                  const float* __restrict__ Gpre,  // 64 x 512
                                                  const float* __restrict__ h0row, // 128
                                                  const float* __restrict__ c0row, // 128
                                                  float* __restrict__ hout)        // 64 x 128
{
    __shared__ float hbuf[2][128];
    __shared__ float part[2][512];
    const int tid = threadIdx.x;
    const int u = tid & 511;
    const int p = tid >> 9;               // k-half, uniform per wave
    float w[64];
    const float4* wr = reinterpret_cast<const float4*>(Whh + (size_t)u * 128 + (size_t)p * 64);
#pragma unroll
    for (int i = 0; i < 16; ++i) {
        float4 t4 = wr[i];
        w[4 * i + 0] = t4.x; w[4 * i + 1] = t4.y; w[4 * i + 2] = t4.z; w[4 * i + 3] = t4.w;
    }
    float c = 0.f;
    if (tid < 128) { hbuf[0][tid] = h0row[tid]; c = c0row[tid]; }
    __syncthreads();
    for (int t = 0; t < 64; ++t) {
        float gp = (p == 0) ? Gpre[t * G4 + u] : 0.f;
        const float* h = hbuf[t & 1] + p * 64;
        float a0 = 0.f, a1 = 0.f, a2 = 0.f, a3 = 0.f;
#pragma unroll
        for (int k = 0; k < 64; k += 4) {
            float4 hv = *reinterpret_cast<const float4*>(h + k);   // uniform broadcast
            a0 = fmaf(w[k + 0], hv.x, a0);
            a1 = fmaf(w[k + 1], hv.y, a1);
            a2 = fmaf(w[k + 2], hv.z, a2);
            a3 = fmaf(w[k + 3], hv.w, a3);
        }
        part[p][u] = gp + ((a0 + a1) + (a2 + a3));
        __syncthreads();
        if (tid < 128) {
            float gi = part[0][tid]       + part[1][tid];
            float gf = part[0][tid + 128] + part[1][tid + 128];
            float gg = part[0][tid + 256] + part[1][tid + 256];
            float go = part[0][tid + 384] + part[1][tid + 384];
            float si = sigmoid_fast(gi);
            float sf = sigmoid_fast(gf);
            float so = sigmoid_fast(go);
            c = sf * c + si * tanh_fast(gg);
            float hn = so * tanh_fast(c);
            hbuf[(t + 1) & 1][tid] = hn;
            hout[t * 128 + tid] = hn;
        }
        __syncthreads();
    }
}

// ---------------- logits: 64 x 128001 ----------------
// 512 threads: lane-half owns b 0..31 or 32..63; each thread 2 v-rows x 32 b.
// acc[2][32] = 64 VGPR -> no spill (launch_bounds(512,2) allows 256 VGPR).
// fcW read once per block (both b-halves share it via L1/L2).
__global__ __launch_bounds__(512, 2) void k_fc(const float* __restrict__ out64,
                                               const float* __restrict__ fcW,
                                               const float* __restrict__ fcb,
                                               float* __restrict__ logits)
{
    __shared__ float ol[64][128];
    const int tid = threadIdx.x;
    for (int i = tid; i < 64 * 128; i += 512) ol[i >> 7][i & 127] = out64[i];
    __syncthreads();
    const int lane = tid & 255;            // v-lane within tile
    const int bh   = tid >> 8;             // b-half: 0 or 1
    const int b0   = bh * 32;
    const int v0   = blockIdx.x * 512 + lane;
    const int v1   = v0 + 256;
    const int vc0  = v0 < V ? v0 : V - 1;
    const int vc1  = v1 < V ? v1 : V - 1;
    const float4* W0 = reinterpret_cast<const float4*>(fcW + (size_t)vc0 * 128);
    const float4* W1 = reinterpret_cast<const float4*>(fcW + (size_t)vc1 * 128);
    const float fb0 = fcb[vc0], fb1 = fcb[vc1];
    float acc[2][32];
#pragma unroll
    for (int bb = 0; bb < 32; ++bb) { acc[0][bb] = fb0; acc[1][bb] = fb1; }
    for (int k4 = 0; k4 < 32; ++k4) {
        float4 w0 = W0[k4];
        float4 w1 = W1[k4];
#pragma unroll
        for (int bb = 0; bb < 32; ++bb) {
            float4 a = *reinterpret_cast<const float4*>(&ol[b0 + bb][k4 * 4]);  // wave-uniform broadcast
            acc[0][bb] += w0.x * a.x + w0.y * a.y + w0.z * a.z + w0.w * a.w;
            acc[1][bb] += w1.x * a.x + w1.y * a.y + w1.z * a.z + w1.w * a.w;
        }
    }
    if (v0 < V) {
#pragma unroll
        for (int bb = 0; bb < 32; ++bb)
            logits[(size_t)(b0 + bb) * V + v0] = acc[0][bb];
    }
    if (v1 < V) {
#pragma unroll
        for (int bb = 0; bb < 32; ++bb)
            logits[(size_t)(b0 + bb) * V + v1] = acc[1][bb];
    }
}

extern "C" void kernel_launch(void* const* d_in, const int* in_sizes, int n_in,
                              void* d_out, int out_size, void* d_ws, size_t ws_size,
                              hipStream_t stream)
{
    const int*   gnodes = (const int*)d_in[0];
    const int*   src    = (const int*)d_in[1];
    const int*   dst    = (const int*)d_in[2];
    const float* emb    = (const float*)d_in[3];
    const float* gW     = (const float*)d_in[4];
    const float* gb     = (const float*)d_in[5];
    const float* Wih0   = (const float*)d_in[6];
    const float* Whh0   = (const float*)d_in[7];
    const float* bih0   = (const float*)d_in[8];
    const float* bhh0   = (const float*)d_in[9];
    const float* Wih1   = (const float*)d_in[10];
    const float* Whh1   = (const float*)d_in[11];
    const float* bih1   = (const float*)d_in[12];
    const float* bhh1   = (const float*)d_in[13];
    const float* fcW    = (const float*)d_in[14];
    const float* fcb    = (const float*)d_in[15];
    const float* h0     = (const float*)d_in[16];  // (2, 200, 128)
    const float* c0     = (const float*)d_in[17];

    char* ws = (char*)d_ws;
    int*   deg_out = (int*)(ws + 0);          // 12800 ints
    int*   degr    = (int*)(ws + 51200);      // 64 ints
    int*   ecount  = (int*)(ws + 51456);      // 1 int (+pad)
    float* agg64   = (float*)(ws + 51712);    // 64*128  -> zero region ends at 84480
    int2*  elist   = (int2*)(ws + 84480);     // CAP entries (64 KB)
    float* h64     = (float*)(ws + 150016);   // 64*128
    float* Gpre    = (float*)(ws + 182784);   // 64*512
    float* h1out   = (float*)(ws + 313856);   // 64*128
    float* out64   = (float*)(ws + 346624);   // 64*128
    float* logits  = (float*)d_out;

    hipMemsetAsync(ws, 0, 84480, stream);     // deg_out, degr, ecount, agg64

    k_deg_filter<<<E / 256, 256, 0, stream>>>(src, dst, deg_out, degr, ecount, elist);
    k_agg<<<CAP / 2, 256, 0, stream>>>(elist, ecount, gnodes, emb, deg_out, agg64);
    k_h64<<<1, 512, 0, stream>>>(agg64, degr, gW, gb, h64);

    k_gemmG<<<8, 256, 0, stream>>>(h64, Wih0, bih0, bhh0, Gpre);
    k_lstm<<<1, 1024, 0, stream>>>(Whh0, Gpre, h0 + 199 * 128, c0 + 199 * 128, h1out);
    k_gemmG<<<8, 256, 0, stream>>>(h1out, Wih1, bih1, bhh1, Gpre);
    k_lstm<<<1, 1024, 0, stream>>>(Whh1, Gpre, h0 + (200 + 199) * 128, c0 + (200 + 199) * 128, out64);

    k_fc<<<251, 512, 0, stream>>>(out64, fcW, fcb, logits);
}